// Round 1
// baseline (440.888 us; speedup 1.0000x reference)
//
#include <hip/hip_runtime.h>
#include <hip/hip_cooperative_groups.h>
#include <stdint.h>

namespace cg = cooperative_groups;

// FrequencySemanticCipher: enc = image + idwt(noise/maxabs), then per-batch min-max norm.
// PRNG: JAX threefry2x32, jax_threefry_partitionable=True semantics.
//
// R3: single persistent cooperative kernel. The 6-kernel chain spent ~190us outside
// the VALU-bound k_enc (tiny serializing kernels, dispatch gaps, k_norm's 200MB
// round trip). Fused: phaseA bits-minmax -> grid.sync -> phaseB scales (redundant
// per-block reduce, no atomics) -> phaseC enc+batch partials -> grid.sync ->
// phaseD batch scale + normalize own chunk (L2/L3-warm re-read).
// Subkeys are compile-time constants (threefry of constants).
// Fallback to the verified 6-kernel path if cooperative launch fails or ws too small.

#define NB    1024
#define NTHR  256
#define NT    (NB * NTHR)        // 262144 persistent threads
#define NSUB  6291456u           // 32*3*256*256 elements per subband
#define EPA   24                 // NSUB / NT
#define CQ    6144u              // quads per block in phase C/D  (6291456/NB)
#define EPC   24                 // CQ / NTHR
#define CHW4  196608             // 3*512*512/4 (float4 per batch) — fallback
#define EPT   64                 // fallback k_noise_minmax elems/thread
#define FLT_BIG 3.402823466e+38f

// ws layout (uint32 words), fused path — no init needed (write-before-read):
// [0 .. 8192)      phase-A partials: blk*8 + s*2 + {0: bmax, 1: ~bmin}
// [8192 .. 9216)   phase-C per-block min (float)
// [9216 .. 10240)  phase-C per-block max (float)
// Fallback path uses its original layout (disjoint semantics, self-initializing).

struct U2 { uint32_t x, y; };

__host__ __device__ constexpr U2 threefry(uint32_t k0, uint32_t k1, uint32_t x0, uint32_t x1) {
  uint32_t ks2 = k0 ^ k1 ^ 0x1BD11BDAu;
  x0 += k0; x1 += k1;
#define TF_R(r) { x0 += x1; x1 = (x1 << (r)) | (x1 >> (32 - (r))); x1 ^= x0; }
  TF_R(13) TF_R(15) TF_R(26) TF_R(6)
  x0 += k1; x1 += ks2 + 1u;
  TF_R(17) TF_R(29) TF_R(16) TF_R(24)
  x0 += ks2; x1 += k0 + 2u;
  TF_R(13) TF_R(15) TF_R(26) TF_R(6)
  x0 += k0; x1 += k1 + 3u;
  TF_R(17) TF_R(29) TF_R(16) TF_R(24)
  x0 += k1; x1 += ks2 + 4u;
  TF_R(13) TF_R(15) TF_R(26) TF_R(6)
  x0 += ks2; x1 += k0 + 5u;
#undef TF_R
  return U2{x0, x1};
}

// subkey_i = threefry((0,123),(0,i)) — pure constants, folded at compile time.
constexpr U2 SK0 = threefry(0u, 123u, 0u, 0u);
constexpr U2 SK1 = threefry(0u, 123u, 0u, 1u);
constexpr U2 SK2 = threefry(0u, 123u, 0u, 2u);
constexpr U2 SK3 = threefry(0u, 123u, 0u, 3u);

__device__ __forceinline__ uint32_t tf_fold(uint32_t k0, uint32_t k1, uint32_t x1) {
  U2 r = threefry(k0, k1, 0u, x1);
  return r.x ^ r.y;
}

// XLA ErfInv32 (Giles) polynomial
__device__ __forceinline__ float erfinv_f32(float x) {
  float w = -logf(1.0f - x * x);
  float p;
  if (w < 5.0f) {
    w = w - 2.5f;
    p = 2.81022636e-08f;
    p = fmaf(p, w, 3.43273939e-07f);
    p = fmaf(p, w, -3.5233877e-06f);
    p = fmaf(p, w, -4.39150654e-06f);
    p = fmaf(p, w, 0.00021858087f);
    p = fmaf(p, w, -0.00125372503f);
    p = fmaf(p, w, -0.00417768164f);
    p = fmaf(p, w, 0.246640727f);
    p = fmaf(p, w, 1.50140941f);
  } else {
    w = sqrtf(w) - 3.0f;
    p = -0.000200214257f;
    p = fmaf(p, w, 0.000100950558f);
    p = fmaf(p, w, 0.00134934322f);
    p = fmaf(p, w, -0.00367342844f);
    p = fmaf(p, w, 0.00573950773f);
    p = fmaf(p, w, -0.0076224613f);
    p = fmaf(p, w, 0.00943887047f);
    p = fmaf(p, w, 1.00167406f);
    p = fmaf(p, w, 2.83297682f);
  }
  return p * x;
}

__device__ __forceinline__ float normal_from_bits(uint32_t bits) {
  uint32_t fb = (bits >> 9) | 0x3f800000u;
  float f = __uint_as_float(fb) - 1.0f;      // [0,1)
  const float lo = -0.99999994f;
  float u = fmaxf(lo, f * 2.0f + lo);
  return 1.41421354f * erfinv_f32(u);
}

// order-preserving float<->uint map (fallback path)
__device__ __forceinline__ uint32_t map_ord(float f) {
  uint32_t s = __float_as_uint(f);
  return (s & 0x80000000u) ? ~s : (s | 0x80000000u);
}
__device__ __forceinline__ float unmap_ord(uint32_t u) {
  return (u & 0x80000000u) ? __uint_as_float(u ^ 0x80000000u) : __uint_as_float(~u);
}

// ============================== fused cooperative kernel ==============================

__global__ __launch_bounds__(NTHR, 4) void k_fused(const float* __restrict__ img,
                                                   float* __restrict__ out,
                                                   uint32_t* __restrict__ ws) {
  const int tid = threadIdx.x;
  const int blk = blockIdx.x;
  const int lane = tid & 63, w = tid >> 6;
  const uint32_t gtid = (uint32_t)blk * NTHR + (uint32_t)tid;
  cg::grid_group grid = cg::this_grid();

  __shared__ uint32_t sU[32];          // 4 waves x 8 slots
  __shared__ float sMn[4], sMx[4], sSc[4];

  // ---------------- Phase A: per-subband min/max of folded bits ----------------
  uint32_t acc[8];
  {
    auto sub = [&](uint32_t k0, uint32_t k1, int s2) {
      uint32_t bmax = 0u, bmin = 0xFFFFFFFFu;
      #pragma unroll 4
      for (int k = 0; k < EPA; ++k) {
        uint32_t bb = tf_fold(k0, k1, gtid + (uint32_t)k * (uint32_t)NT);
        bmax = max(bmax, bb);
        bmin = min(bmin, bb);
      }
      acc[s2] = bmax; acc[s2 + 1] = ~bmin;   // store ~min so everything reduces with max
    };
    sub(SK0.x, SK0.y, 0);
    sub(SK1.x, SK1.y, 2);
    sub(SK2.x, SK2.y, 4);
    sub(SK3.x, SK3.y, 6);
  }
  #pragma unroll
  for (int off = 32; off > 0; off >>= 1) {
    #pragma unroll
    for (int r = 0; r < 8; ++r)
      acc[r] = max(acc[r], (uint32_t)__shfl_down(acc[r], off));
  }
  if (lane == 0) {
    #pragma unroll
    for (int r = 0; r < 8; ++r) sU[w * 8 + r] = acc[r];
  }
  __syncthreads();
  if (tid < 8) {
    uint32_t v = max(max(sU[tid], sU[8 + tid]), max(sU[16 + tid], sU[24 + tid]));
    ws[(uint32_t)blk * 8u + (uint32_t)tid] = v;
  }
  grid.sync();

  // ---------------- Phase B: every block reduces all partials -> subband scales ----------------
  {
    const int slot = tid & 7;
    uint32_t v = 0u;
    for (int e = tid >> 3; e < NB; e += 32) v = max(v, ws[(uint32_t)(e * 8 + slot)]);  // = ws[tid+256j], coalesced
    v = max(v, (uint32_t)__shfl_down(v, 32));
    v = max(v, (uint32_t)__shfl_down(v, 16));
    v = max(v, (uint32_t)__shfl_down(v, 8));
    if (lane < 8) sU[w * 8 + lane] = v;
    __syncthreads();
    if (tid < 8) {
      uint32_t r = max(max(sU[tid], sU[8 + tid]), max(sU[16 + tid], sU[24 + tid]));
      sU[tid] = r;   // thread t only touches sU[t], sU[t+8k]: no cross-thread hazard
    }
    __syncthreads();
    if (tid < 4) {
      uint32_t bmax = sU[2 * tid], bmin = ~sU[2 * tid + 1];
      float nmax = normal_from_bits(bmax);
      float nmin = normal_from_bits(bmin);
      sSc[tid] = 1.0f / (fmaxf(nmax, -nmin) + 1e-8f);
    }
    __syncthreads();
  }
  const float sc0 = sSc[0], sc1 = sSc[1], sc2 = sSc[2], sc3 = sSc[3];

  // ---------------- Phase C: enc = img + idwt(noise), per-block min/max partials ----------------
  // Block owns quads [blk*CQ, (blk+1)*CQ) — contiguous 24576-float region, single batch
  // (CQ*32 blocks == 196608 quads per batch, exact).  q IS the PRNG index: ((b*3+c)<<16)|(i<<8)|j.
  float vmin = FLT_BIG, vmax = -FLT_BIG;
  const uint32_t q0 = (uint32_t)blk * CQ;
  for (int k = 0; k < EPC; ++k) {
    const uint32_t q = q0 + (uint32_t)(k * NTHR) + (uint32_t)tid;
    const uint32_t bc = q >> 16;
    const uint32_t i  = (q >> 8) & 255u;
    const uint32_t j  = q & 255u;
    const size_t base = (size_t)bc * 262144u + (size_t)i * 1024u + 2u * (size_t)j;
    const float2 r0 = *(const float2*)(img + base);         // issued before the VALU storm
    const float2 r1 = *(const float2*)(img + base + 512);
    const float n0 = normal_from_bits(tf_fold(SK0.x, SK0.y, q)) * sc0;
    const float n1 = normal_from_bits(tf_fold(SK1.x, SK1.y, q)) * sc1;
    const float n2 = normal_from_bits(tf_fold(SK2.x, SK2.y, q)) * sc2;
    const float n3 = normal_from_bits(tf_fold(SK3.x, SK3.y, q)) * sc3;
    const float qa = 0.5f * (n0 + n1 + n2 + n3);
    const float qb = 0.5f * (n0 + n1 - n2 - n3);
    const float qc = 0.5f * (n0 - n1 + n2 - n3);
    const float qd = 0.5f * (n0 - n1 - n2 + n3);
    const float e00 = r0.x + qa, e01 = r0.y + qb;
    const float e10 = r1.x + qc, e11 = r1.y + qd;
    *(float2*)(out + base) = make_float2(e00, e01);
    *(float2*)(out + base + 512) = make_float2(e10, e11);
    vmin = fminf(vmin, fminf(fminf(e00, e01), fminf(e10, e11)));
    vmax = fmaxf(vmax, fmaxf(fmaxf(e00, e01), fmaxf(e10, e11)));
  }
  #pragma unroll
  for (int off = 32; off > 0; off >>= 1) {
    vmin = fminf(vmin, __shfl_down(vmin, off));
    vmax = fmaxf(vmax, __shfl_down(vmax, off));
  }
  if (lane == 0) { sMn[w] = vmin; sMx[w] = vmax; }
  __syncthreads();
  if (tid == 0) {
    vmin = fminf(fminf(sMn[0], sMn[1]), fminf(sMn[2], sMn[3]));
    vmax = fmaxf(fmaxf(sMx[0], sMx[1]), fmaxf(sMx[2], sMx[3]));
    ((float*)ws)[8192 + blk] = vmin;
    ((float*)ws)[9216 + blk] = vmax;
  }
  grid.sync();

  // ---------------- Phase D: batch scale + normalize own chunk ----------------
  {
    const uint32_t bb = (uint32_t)blk >> 5;          // 32 blocks per batch
    if (tid < 64) {                                  // wave 0 only
      float pmn = (lane < 32) ? ((const float*)ws)[8192 + bb * 32 + (uint32_t)lane] :  FLT_BIG;
      float pmx = (lane < 32) ? ((const float*)ws)[9216 + bb * 32 + (uint32_t)lane] : -FLT_BIG;
      #pragma unroll
      for (int off = 16; off > 0; off >>= 1) {
        pmn = fminf(pmn, __shfl_down(pmn, off));
        pmx = fmaxf(pmx, __shfl_down(pmx, off));
      }
      if (lane == 0) { sMn[0] = pmn; sMx[0] = pmx; }
    }
    __syncthreads();
    const float mn  = sMn[0];
    const float inv = 1.0f / fmaxf(sMx[0] - mn, 1e-8f);
    float4* o4 = (float4*)out;
    const uint32_t f0 = (uint32_t)blk * CQ;          // float4 index base == quad base
    #pragma unroll 4
    for (int k = 0; k < EPC; ++k) {
      const uint32_t x = f0 + (uint32_t)(k * NTHR) + (uint32_t)tid;
      float4 v = o4[x];
      v.x = (v.x - mn) * inv;
      v.y = (v.y - mn) * inv;
      v.z = (v.z - mn) * inv;
      v.w = (v.w - mn) * inv;
      o4[x] = v;
    }
  }
}

// ============================== fallback: verified 6-kernel path ==============================

__global__ void k_init(uint32_t* ws) {
  int t = threadIdx.x;
  if (t == 0) {
    for (int i = 0; i < 4; ++i) {
      U2 r = threefry(0u, 123u, 0u, (uint32_t)i);
      ws[2 * i] = r.x;
      ws[2 * i + 1] = r.y;
    }
  }
  if (t < 4) {
    ws[16 + 16 * t] = 0u;
    ws[80 + 16 * t] = 0xFFFFFFFFu;
  }
  if (t < 32) {
    ws[160 + 32 * t] = 0xFFFFFFFFu;
    ws[160 + 32 * t + 16] = 0u;
  }
}

__global__ __launch_bounds__(256) void k_noise_minmax(uint32_t* __restrict__ ws) {
  const int s = blockIdx.y;
  const uint32_t k0 = ws[2 * s], k1 = ws[2 * s + 1];
  const uint32_t base = blockIdx.x * (256u * EPT) + threadIdx.x;
  uint32_t bmax = 0u, bmin = 0xFFFFFFFFu;
  #pragma unroll 8
  for (int k = 0; k < EPT; ++k) {
    uint32_t b = tf_fold(k0, k1, base + (uint32_t)k * 256u);
    bmax = max(bmax, b);
    bmin = min(bmin, b);
  }
  #pragma unroll
  for (int off = 32; off > 0; off >>= 1) {
    bmax = max(bmax, (uint32_t)__shfl_down(bmax, off));
    bmin = min(bmin, (uint32_t)__shfl_down(bmin, off));
  }
  __shared__ uint32_t smax[4], smin[4];
  const int lane = threadIdx.x & 63, w = threadIdx.x >> 6;
  if (lane == 0) { smax[w] = bmax; smin[w] = bmin; }
  __syncthreads();
  if (threadIdx.x == 0) {
    bmax = max(max(smax[0], smax[1]), max(smax[2], smax[3]));
    bmin = min(min(smin[0], smin[1]), min(smin[2], smin[3]));
    atomicMax(&ws[16 + 16 * s], bmax);
    atomicMin(&ws[80 + 16 * s], bmin);
  }
}

__global__ void k_scales(uint32_t* ws) {
  int s = threadIdx.x;
  if (s < 4) {
    float nmax = normal_from_bits(ws[16 + 16 * s]);
    float nmin = normal_from_bits(ws[80 + 16 * s]);
    float mabs = fmaxf(nmax, -nmin);
    ((float*)ws)[144 + s] = 1.0f / (mabs + 1e-8f);
  }
}

__global__ __launch_bounds__(256) void k_enc(const float* __restrict__ img,
                                             float* __restrict__ out,
                                             uint32_t* __restrict__ ws) {
  const int j = threadIdx.x;
  const int i = blockIdx.x;
  const int c = blockIdx.y;
  const int b = blockIdx.z;
  const uint32_t idx = ((uint32_t)(b * 3 + c) << 16) | ((uint32_t)i << 8) | (uint32_t)j;
  const float* wsf = (const float*)ws;
  float n0 = normal_from_bits(tf_fold(ws[0], ws[1], idx)) * wsf[144];
  float n1 = normal_from_bits(tf_fold(ws[2], ws[3], idx)) * wsf[145];
  float n2 = normal_from_bits(tf_fold(ws[4], ws[5], idx)) * wsf[146];
  float n3 = normal_from_bits(tf_fold(ws[6], ws[7], idx)) * wsf[147];
  float qa = 0.5f * (n0 + n1 + n2 + n3);
  float qb = 0.5f * (n0 + n1 - n2 - n3);
  float qc = 0.5f * (n0 - n1 + n2 - n3);
  float qd = 0.5f * (n0 - n1 - n2 + n3);
  size_t base = ((size_t)(b * 3 + c) * 512 + 2 * i) * 512 + 2 * j;
  const float2 r0 = *(const float2*)(img + base);
  const float2 r1 = *(const float2*)(img + base + 512);
  float e00 = r0.x + qa, e01 = r0.y + qb, e10 = r1.x + qc, e11 = r1.y + qd;
  *(float2*)(out + base) = make_float2(e00, e01);
  *(float2*)(out + base + 512) = make_float2(e10, e11);
  float vmin = fminf(fminf(e00, e01), fminf(e10, e11));
  float vmax = fmaxf(fmaxf(e00, e01), fmaxf(e10, e11));
  #pragma unroll
  for (int off = 32; off > 0; off >>= 1) {
    vmin = fminf(vmin, __shfl_down(vmin, off));
    vmax = fmaxf(vmax, __shfl_down(vmax, off));
  }
  __shared__ float smin[4], smax[4];
  const int lane = threadIdx.x & 63, w = threadIdx.x >> 6;
  if (lane == 0) { smin[w] = vmin; smax[w] = vmax; }
  __syncthreads();
  if (threadIdx.x == 0) {
    vmin = fminf(fminf(smin[0], smin[1]), fminf(smin[2], smin[3]));
    vmax = fmaxf(fmaxf(smax[0], smax[1]), fmaxf(smax[2], smax[3]));
    atomicMin(&ws[160 + 32 * b], map_ord(vmin));
    atomicMax(&ws[160 + 32 * b + 16], map_ord(vmax));
  }
}

__global__ void k_batch_scale(uint32_t* ws) {
  int b = threadIdx.x;
  if (b < 32) {
    float mn = unmap_ord(ws[160 + 32 * b]);
    float mx = unmap_ord(ws[160 + 32 * b + 16]);
    ((float*)ws)[1184 + b] = mn;
    ((float*)ws)[1216 + b] = 1.0f / fmaxf(mx - mn, 1e-8f);
  }
}

__global__ __launch_bounds__(256) void k_norm(float* __restrict__ out,
                                              const uint32_t* __restrict__ ws) {
  const int idx = blockIdx.x * 256 + threadIdx.x;
  const int b = idx / CHW4;
  const float mn = ((const float*)ws)[1184 + b];
  const float inv = ((const float*)ws)[1216 + b];
  float4 v = ((float4*)out)[idx];
  v.x = (v.x - mn) * inv;
  v.y = (v.y - mn) * inv;
  v.z = (v.z - mn) * inv;
  v.w = (v.w - mn) * inv;
  ((float4*)out)[idx] = v;
}

extern "C" void kernel_launch(void* const* d_in, const int* in_sizes, int n_in,
                              void* d_out, int out_size, void* d_ws, size_t ws_size,
                              hipStream_t stream) {
  const float* img = (const float*)d_in[0];
  float* out = (float*)d_out;
  uint32_t* ws = (uint32_t*)d_ws;

  hipError_t err = hipErrorUnknown;
  if (ws_size >= 10240u * sizeof(uint32_t)) {
    void* kargs[] = {(void*)&img, (void*)&out, (void*)&ws};
    err = hipLaunchCooperativeKernel((const void*)k_fused, dim3(NB), dim3(NTHR),
                                     kargs, 0, stream);
  }
  if (err != hipSuccess) {
    (void)hipGetLastError();  // clear sticky error, fall back to verified path
    k_init<<<1, 64, 0, stream>>>(ws);
    k_noise_minmax<<<dim3(NSUB / (256 * EPT), 4, 1), 256, 0, stream>>>(ws);
    k_scales<<<1, 64, 0, stream>>>(ws);
    k_enc<<<dim3(256, 3, 32), 256, 0, stream>>>(img, out, ws);
    k_batch_scale<<<1, 64, 0, stream>>>(ws);
    k_norm<<<NSUB / 256, 256, 0, stream>>>(out, ws);
  }
}

// Round 2
// 271.203 us; speedup vs baseline: 1.6257x; 1.6257x over previous
//
#include <hip/hip_runtime.h>
#include <stdint.h>

// FrequencySemanticCipher: enc = image + idwt(noise/maxabs), then per-batch min-max norm.
// PRNG: JAX threefry2x32, jax_threefry_partitionable=True semantics.
//
// R2 lesson [counters]: atomics resolve memory-side; give each target its own 64B line.
// R3 lesson [counters]: cooperative fusion loses — grid.sync + 4-blk/CU occupancy cost
//   ~200us of non-issue vs ~20us of fusable gap. Chain of flat-occupancy kernels wins.
// R4 (this): k_enc was ~1000 instr/quad at 90% VALUBusy; OCML logf (x4 per quad) is the
//   bloat. v_log_f32 is a single quarter-rate instr: w = -ln2*log2(1-u^2).
//   Chain compressed 6->4 kernels: k_init folded into k_scales (minmax is atomic-free
//   partials now), k_batch_scale folded into k_norm (block-uniform scalar math).
//
// ws layout (uint32 words), all written-before-read every iteration (graph-replay safe):
// [0 .. 3072)      minmax partials: (s*384 + blk)*2 + {0: bmax, 1: bmin}
// [3200 .. 3204)   per-subband scale = sqrt2/(maxabs+eps)  (float)
// [3328 + 32*b]    batch mapped min (b<32, init 0xFFFFFFFF by k_scales)
// [3328 + 32*b+16] batch mapped max (init 0)

#define NSUB  6291456u      // 32*3*256*256 elements per subband
#define EPT   64            // elems/thread in k_minmax
#define MMB   384           // minmax blocks per subband = NSUB/(256*EPT)
#define PART  0
#define SC    3200
#define BMM   3328
#define NORM_B4 512         // float4s per k_norm block (2 per thread)

struct U2 { uint32_t x, y; };

__host__ __device__ constexpr U2 threefry(uint32_t k0, uint32_t k1, uint32_t x0, uint32_t x1) {
  uint32_t ks2 = k0 ^ k1 ^ 0x1BD11BDAu;
  x0 += k0; x1 += k1;
#define TF_R(r) { x0 += x1; x1 = (x1 << (r)) | (x1 >> (32 - (r))); x1 ^= x0; }
  TF_R(13) TF_R(15) TF_R(26) TF_R(6)
  x0 += k1; x1 += ks2 + 1u;
  TF_R(17) TF_R(29) TF_R(16) TF_R(24)
  x0 += ks2; x1 += k0 + 2u;
  TF_R(13) TF_R(15) TF_R(26) TF_R(6)
  x0 += k0; x1 += k1 + 3u;
  TF_R(17) TF_R(29) TF_R(16) TF_R(24)
  x0 += k1; x1 += ks2 + 4u;
  TF_R(13) TF_R(15) TF_R(26) TF_R(6)
  x0 += ks2; x1 += k0 + 5u;
#undef TF_R
  return U2{x0, x1};
}

// subkey_i = threefry((0,123),(0,i)) — compile-time constants.
constexpr U2 SK0 = threefry(0u, 123u, 0u, 0u);
constexpr U2 SK1 = threefry(0u, 123u, 0u, 1u);
constexpr U2 SK2 = threefry(0u, 123u, 0u, 2u);
constexpr U2 SK3 = threefry(0u, 123u, 0u, 3u);

__device__ __forceinline__ uint32_t tf_fold(uint32_t k0, uint32_t k1, uint32_t x1) {
  U2 r = threefry(k0, k1, 0u, x1);
  return r.x ^ r.y;
}

__device__ __forceinline__ float fast_log2(float x) {
#if __has_builtin(__builtin_amdgcn_logf)
  return __builtin_amdgcn_logf(x);     // v_log_f32: D = log2(S0)
#else
  return __log2f(x);                   // HIP native log2 -> v_log_f32
#endif
}

// erfinv core WITHOUT the sqrt(2) factor: returns p*u. Native-log variant (hot path).
__device__ __forceinline__ float normal_core(uint32_t bits) {
  uint32_t fb = (bits >> 9) | 0x3f800000u;
  float f = __uint_as_float(fb) - 1.0f;          // [0,1)
  const float lo = -0.99999994f;
  float u = fmaxf(lo, f * 2.0f + lo);
  float w = -0.69314718056f * fast_log2(1.0f - u * u);   // = -ln(1-u^2)
  float p;
  if (w < 5.0f) {
    w = w - 2.5f;
    p = 2.81022636e-08f;
    p = fmaf(p, w, 3.43273939e-07f);
    p = fmaf(p, w, -3.5233877e-06f);
    p = fmaf(p, w, -4.39150654e-06f);
    p = fmaf(p, w, 0.00021858087f);
    p = fmaf(p, w, -0.00125372503f);
    p = fmaf(p, w, -0.00417768164f);
    p = fmaf(p, w, 0.246640727f);
    p = fmaf(p, w, 1.50140941f);
  } else {
    w = sqrtf(w) - 3.0f;
    p = -0.000200214257f;
    p = fmaf(p, w, 0.000100950558f);
    p = fmaf(p, w, 0.00134934322f);
    p = fmaf(p, w, -0.00367342844f);
    p = fmaf(p, w, 0.00573950773f);
    p = fmaf(p, w, -0.0076224613f);
    p = fmaf(p, w, 0.00943887047f);
    p = fmaf(p, w, 1.00167406f);
    p = fmaf(p, w, 2.83297682f);
  }
  return p * u;
}

// Precise variant (OCML logf) for the 4 scale values only — matches R0-verified numerics
// where it matters most (the global scale applied to every noise sample).
__device__ __forceinline__ float normal_precise(uint32_t bits) {
  uint32_t fb = (bits >> 9) | 0x3f800000u;
  float f = __uint_as_float(fb) - 1.0f;
  const float lo = -0.99999994f;
  float u = fmaxf(lo, f * 2.0f + lo);
  float w = -logf(1.0f - u * u);
  float p;
  if (w < 5.0f) {
    w = w - 2.5f;
    p = 2.81022636e-08f;
    p = fmaf(p, w, 3.43273939e-07f);
    p = fmaf(p, w, -3.5233877e-06f);
    p = fmaf(p, w, -4.39150654e-06f);
    p = fmaf(p, w, 0.00021858087f);
    p = fmaf(p, w, -0.00125372503f);
    p = fmaf(p, w, -0.00417768164f);
    p = fmaf(p, w, 0.246640727f);
    p = fmaf(p, w, 1.50140941f);
  } else {
    w = sqrtf(w) - 3.0f;
    p = -0.000200214257f;
    p = fmaf(p, w, 0.000100950558f);
    p = fmaf(p, w, 0.00134934322f);
    p = fmaf(p, w, -0.00367342844f);
    p = fmaf(p, w, 0.00573950773f);
    p = fmaf(p, w, -0.0076224613f);
    p = fmaf(p, w, 0.00943887047f);
    p = fmaf(p, w, 1.00167406f);
    p = fmaf(p, w, 2.83297682f);
  }
  return 1.41421354f * p * u;
}

// order-preserving float<->uint map
__device__ __forceinline__ uint32_t map_ord(float f) {
  uint32_t s = __float_as_uint(f);
  return (s & 0x80000000u) ? ~s : (s | 0x80000000u);
}
__device__ __forceinline__ float unmap_ord(uint32_t u) {
  return (u & 0x80000000u) ? __uint_as_float(u ^ 0x80000000u) : __uint_as_float(~u);
}

// K1: per-subband min/max of folded bits -> per-block partials (no atomics, no init).
__global__ __launch_bounds__(256) void k_minmax(uint32_t* __restrict__ ws) {
  const int s = blockIdx.y;
  const uint32_t k0 = (s == 0) ? SK0.x : (s == 1) ? SK1.x : (s == 2) ? SK2.x : SK3.x;
  const uint32_t k1 = (s == 0) ? SK0.y : (s == 1) ? SK1.y : (s == 2) ? SK2.y : SK3.y;
  const uint32_t base = blockIdx.x * (256u * EPT) + threadIdx.x;
  uint32_t bmax = 0u, bmin = 0xFFFFFFFFu;
  #pragma unroll 8
  for (int k = 0; k < EPT; ++k) {
    uint32_t b = tf_fold(k0, k1, base + (uint32_t)k * 256u);
    bmax = max(bmax, b);
    bmin = min(bmin, b);
  }
  #pragma unroll
  for (int off = 32; off > 0; off >>= 1) {
    bmax = max(bmax, (uint32_t)__shfl_down(bmax, off));
    bmin = min(bmin, (uint32_t)__shfl_down(bmin, off));
  }
  __shared__ uint32_t smax[4], smin[4];
  const int lane = threadIdx.x & 63, w = threadIdx.x >> 6;
  if (lane == 0) { smax[w] = bmax; smin[w] = bmin; }
  __syncthreads();
  if (threadIdx.x == 0) {
    bmax = max(max(smax[0], smax[1]), max(smax[2], smax[3]));
    bmin = min(min(smin[0], smin[1]), min(smin[2], smin[3]));
    ws[PART + (s * MMB + blockIdx.x) * 2]     = bmax;
    ws[PART + (s * MMB + blockIdx.x) * 2 + 1] = bmin;
  }
}

// K2: reduce partials -> subband scales; also init the batch min/max atomic slots.
__global__ void k_scales(uint32_t* __restrict__ ws) {
  const int tid = threadIdx.x;
  const int s = tid >> 6, lane = tid & 63;    // wave s handles subband s
  uint32_t bmax = 0u, bmin = 0xFFFFFFFFu;
  #pragma unroll
  for (int e = 0; e < MMB; e += 64) {
    bmax = max(bmax, ws[PART + (s * MMB + e + lane) * 2]);
    bmin = min(bmin, ws[PART + (s * MMB + e + lane) * 2 + 1]);
  }
  #pragma unroll
  for (int off = 32; off > 0; off >>= 1) {
    bmax = max(bmax, (uint32_t)__shfl_down(bmax, off));
    bmin = min(bmin, (uint32_t)__shfl_down(bmin, off));
  }
  if (lane == 0) {
    float nmax = normal_precise(bmax);
    float nmin = normal_precise(bmin);
    float mabs = fmaxf(nmax, -nmin);
    // sqrt2 folded out of k_enc's normal_core into the scale
    ((float*)ws)[SC + s] = 1.41421354f / (mabs + 1e-8f) / 1.41421354f * 1.41421354f;
  }
  if (tid < 32) {
    ws[BMM + 32 * tid]      = 0xFFFFFFFFu;
    ws[BMM + 32 * tid + 16] = 0u;
  }
}

// K3: enc = image + idwt(scaled noise); per-batch min/max via 2 atomics/block.
__global__ __launch_bounds__(256) void k_enc(const float* __restrict__ img,
                                             float* __restrict__ out,
                                             uint32_t* __restrict__ ws) {
  const int j = threadIdx.x;       // 0..255
  const int i = blockIdx.x;        // 0..255
  const int c = blockIdx.y;        // 0..2
  const int b = blockIdx.z;        // 0..31
  const uint32_t idx = ((uint32_t)(b * 3 + c) << 16) | ((uint32_t)i << 8) | (uint32_t)j;
  const float* wsf = (const float*)ws;
  const float n0 = normal_core(tf_fold(SK0.x, SK0.y, idx)) * wsf[SC + 0];
  const float n1 = normal_core(tf_fold(SK1.x, SK1.y, idx)) * wsf[SC + 1];
  const float n2 = normal_core(tf_fold(SK2.x, SK2.y, idx)) * wsf[SC + 2];
  const float n3 = normal_core(tf_fold(SK3.x, SK3.y, idx)) * wsf[SC + 3];
  const float qa = 0.5f * (n0 + n1 + n2 + n3);
  const float qb = 0.5f * (n0 + n1 - n2 - n3);
  const float qc = 0.5f * (n0 - n1 + n2 - n3);
  const float qd = 0.5f * (n0 - n1 - n2 + n3);
  size_t base = ((size_t)(b * 3 + c) * 512 + 2 * i) * 512 + 2 * j;
  const float2 r0 = *(const float2*)(img + base);
  const float2 r1 = *(const float2*)(img + base + 512);
  const float e00 = r0.x + qa, e01 = r0.y + qb;
  const float e10 = r1.x + qc, e11 = r1.y + qd;
  *(float2*)(out + base) = make_float2(e00, e01);
  *(float2*)(out + base + 512) = make_float2(e10, e11);
  float vmin = fminf(fminf(e00, e01), fminf(e10, e11));
  float vmax = fmaxf(fmaxf(e00, e01), fmaxf(e10, e11));
  #pragma unroll
  for (int off = 32; off > 0; off >>= 1) {
    vmin = fminf(vmin, __shfl_down(vmin, off));
    vmax = fmaxf(vmax, __shfl_down(vmax, off));
  }
  __shared__ float smin[4], smax[4];
  const int lane = threadIdx.x & 63, w = threadIdx.x >> 6;
  if (lane == 0) { smin[w] = vmin; smax[w] = vmax; }
  __syncthreads();
  if (threadIdx.x == 0) {
    vmin = fminf(fminf(smin[0], smin[1]), fminf(smin[2], smin[3]));
    vmax = fmaxf(fmaxf(smax[0], smax[1]), fmaxf(smax[2], smax[3]));
    atomicMin(&ws[BMM + 32 * b], map_ord(vmin));
    atomicMax(&ws[BMM + 32 * b + 16], map_ord(vmax));
  }
}

// K4: in-place per-batch min-max normalize. Batch index is block-uniform (scalar path);
// scale math done once per block (k_batch_scale folded in). 2 float4 per thread.
__global__ __launch_bounds__(256) void k_norm(float* __restrict__ out,
                                              const uint32_t* __restrict__ ws) {
  const int bx = blockIdx.x;
  const int b = bx / (196608 / NORM_B4);        // 384 blocks per batch, uniform
  const float mn = unmap_ord(ws[BMM + 32 * b]);
  const float mx = unmap_ord(ws[BMM + 32 * b + 16]);
  const float inv = 1.0f / fmaxf(mx - mn, 1e-8f);
  float4* o4 = (float4*)out;
  const int i0 = bx * NORM_B4 + threadIdx.x;
  float4 v0 = o4[i0];
  float4 v1 = o4[i0 + 256];
  v0.x = (v0.x - mn) * inv; v0.y = (v0.y - mn) * inv;
  v0.z = (v0.z - mn) * inv; v0.w = (v0.w - mn) * inv;
  v1.x = (v1.x - mn) * inv; v1.y = (v1.y - mn) * inv;
  v1.z = (v1.z - mn) * inv; v1.w = (v1.w - mn) * inv;
  o4[i0] = v0;
  o4[i0 + 256] = v1;
}

extern "C" void kernel_launch(void* const* d_in, const int* in_sizes, int n_in,
                              void* d_out, int out_size, void* d_ws, size_t ws_size,
                              hipStream_t stream) {
  const float* img = (const float*)d_in[0];
  float* out = (float*)d_out;
  uint32_t* ws = (uint32_t*)d_ws;

  k_minmax<<<dim3(MMB, 4, 1), 256, 0, stream>>>(ws);
  k_scales<<<1, 256, 0, stream>>>(ws);
  k_enc<<<dim3(256, 3, 32), 256, 0, stream>>>(img, out, ws);
  k_norm<<<NSUB / NORM_B4, 256, 0, stream>>>(out, ws);
}